// Round 2
// baseline (1117.850 us; speedup 1.0000x reference)
//
#include <hip/hip_runtime.h>
#include <stdint.h>

#define NN 50000
#define NE 1600000
#define BE 128

typedef __attribute__((ext_vector_type(8))) short short8;
typedef __attribute__((ext_vector_type(4))) float f32x4;

__device__ __forceinline__ unsigned short f2bf(float f) {
    unsigned int u = __float_as_uint(f);
    u += 0x7fff + ((u >> 16) & 1);   // round-nearest-even
    return (unsigned short)(u >> 16);
}

__device__ __forceinline__ float silu_f(float v) {
    return v / (1.0f + __expf(-v));
}

// ws layout (ushort units):
// [0,20480)        node_w1^T  [128][160]
// [20480,40960)    coord_w1^T [128][160]
// [40960,49152)    node_w2^T  [64][128]
// [65536,3265536)  h as bf16  [50000][64]
__global__ void prep_w(const float* __restrict__ nw1,
                       const float* __restrict__ cw1,
                       const float* __restrict__ nw2,
                       unsigned short* __restrict__ ws) {
    int i = blockIdx.x * 256 + threadIdx.x;
    if (i < 20480) {
        int n = i / 160, k = i % 160;
        ws[i] = f2bf(nw1[k * 128 + n]);
    } else if (i < 40960) {
        int j = i - 20480; int n = j / 160, k = j % 160;
        ws[i] = f2bf(cw1[k * 128 + n]);
    } else if (i < 49152) {
        int j = i - 40960; int o = j / 128, k = j % 128;
        ws[i] = f2bf(nw2[k * 64 + o]);
    }
}

__global__ void prep_h(const float4* __restrict__ h4,
                       unsigned short* __restrict__ hbf) {
    int i = blockIdx.x * 256 + threadIdx.x;
    if (i < 800000) {
        float4 v = h4[i];
        unsigned short b[4] = {f2bf(v.x), f2bf(v.y), f2bf(v.z), f2bf(v.w)};
        *(uint2*)&hbf[i * 4] = *(uint2*)b;
    }
}

// out[0:3.2M) = h, out[3.2M:3.35M) = x   (float4 units)
__global__ void init_out(const float4* __restrict__ h4,
                         const float4* __restrict__ x4,
                         float4* __restrict__ out4) {
    int i = blockIdx.x * 256 + threadIdx.x;
    if (i < 800000)       out4[i] = h4[i];
    else if (i < 837500)  out4[i] = x4[i - 800000];
}

#define MIS 168   // m_input row stride (ushorts); 336B, 16B-aligned rows

__global__ __launch_bounds__(256, 3)
void egnn_edge_kernel(const float* __restrict__ x,
                      const int* __restrict__ eidx,
                      const float* __restrict__ edist,
                      const float* __restrict__ node_b1,
                      const float* __restrict__ node_b2,
                      const float* __restrict__ coord_b1,
                      const float* __restrict__ coord_w2,
                      const float* __restrict__ ew1,
                      const float* __restrict__ eb1,
                      const float* __restrict__ ew2,
                      const float* __restrict__ eb2,
                      const unsigned short* __restrict__ ws,
                      float* __restrict__ out_h,
                      float* __restrict__ out_x) {
    // LDS: 128*168*2 = 43008 B -> 3 blocks/CU
    __shared__ unsigned short mi[BE * MIS];     // m_input tile, later hidden tile

    const int tid  = threadIdx.x;
    const int w    = tid >> 6;      // wave 0..3, owns edge rows [w*32, w*32+32)
    const int lane = tid & 63;
    const int ln   = lane & 15;
    const int quad = lane >> 4;
    const int e0   = blockIdx.x * BE;
    const unsigned short* hbf = ws + 65536;

    // ---- stage m_input cols 0..127: gather bf16 h[src], h[dst] (16B chunks) ----
    #pragma unroll
    for (int it = 0; it < 8; ++it) {
        int idx = it * 256 + tid;        // 0..2047 = 256 rows x 8 chunks
        int row = idx >> 3, chunk = idx & 7;
        int e = row & 127;
        int node = (row < 128) ? eidx[e0 + e] : eidx[NE + e0 + e];
        int cbase = (row < 128) ? 0 : 64;
        *(uint4*)&mi[e * MIS + cbase + chunk * 8] =
            *(const uint4*)&hbf[node * 64 + chunk * 8];
    }
    // ---- stage m_input cols 128..159: edge MLP (fp32) ----
    {
        int e = tid >> 1, half = tid & 1;
        float d = edist[e0 + e];
        float s[16];
        #pragma unroll
        for (int jj = 0; jj < 16; ++jj) s[jj] = eb2[half * 16 + jj];
        #pragma unroll
        for (int k = 0; k < 32; ++k) {
            float tk = silu_f(d * ew1[k] + eb1[k]);
            const float* r2 = ew2 + k * 32 + half * 16;
            #pragma unroll
            for (int jj = 0; jj < 16; ++jj) s[jj] += tk * r2[jj];
        }
        #pragma unroll
        for (int jj = 0; jj < 16; ++jj)
            mi[e * MIS + 128 + half * 16 + jj] = f2bf(s[jj]);
    }
    __syncthreads();   // the ONLY block-wide barrier

    // ---- GEMM1: node (full acc) + coord (folded per 64-col half) ----
    f32x4 accN[2][8];
    const f32x4 zero = {0.f, 0.f, 0.f, 0.f};
    #pragma unroll
    for (int a = 0; a < 2; ++a)
        #pragma unroll
        for (int b = 0; b < 8; ++b) accN[a][b] = zero;
    float cw[2][4];
    #pragma unroll
    for (int mt = 0; mt < 2; ++mt)
        #pragma unroll
        for (int r = 0; r < 4; ++r) cw[mt][r] = 0.f;

    const int arow0 = (w * 32 + ln) * MIS;
    const int arow1 = (w * 32 + 16 + ln) * MIS;
    const int koff  = quad * 8;

    #pragma unroll
    for (int half = 0; half < 2; ++half) {
        f32x4 accC[2][4];
        #pragma unroll
        for (int a = 0; a < 2; ++a)
            #pragma unroll
            for (int b = 0; b < 4; ++b) accC[a][b] = zero;
        #pragma unroll
        for (int kc = 0; kc < 5; ++kc) {
            short8 a0 = *(const short8*)&mi[arow0 + kc * 32 + koff];
            short8 a1 = *(const short8*)&mi[arow1 + kc * 32 + koff];
            #pragma unroll
            for (int nt = 0; nt < 4; ++nt) {
                const unsigned short* bp =
                    ws + (half * 64 + nt * 16 + ln) * 160 + kc * 32 + koff;
                short8 bN = *(const short8*)bp;
                short8 bC = *(const short8*)(bp + 20480);
                const int nn = half * 4 + nt;
                accN[0][nn] = __builtin_amdgcn_mfma_f32_16x16x32_bf16(a0, bN, accN[0][nn], 0, 0, 0);
                accN[1][nn] = __builtin_amdgcn_mfma_f32_16x16x32_bf16(a1, bN, accN[1][nn], 0, 0, 0);
                accC[0][nt] = __builtin_amdgcn_mfma_f32_16x16x32_bf16(a0, bC, accC[0][nt], 0, 0, 0);
                accC[1][nt] = __builtin_amdgcn_mfma_f32_16x16x32_bf16(a1, bC, accC[1][nt], 0, 0, 0);
            }
        }
        // fold coord half into scalar cw (frees accC regs)
        #pragma unroll
        for (int nt = 0; nt < 4; ++nt) {
            int col = half * 64 + nt * 16 + ln;
            float b1v = coord_b1[col];
            float w2v = coord_w2[col];
            #pragma unroll
            for (int mt = 0; mt < 2; ++mt)
                #pragma unroll
                for (int r = 0; r < 4; ++r)
                    cw[mt][r] += silu_f(accC[mt][nt][r] + b1v) * w2v;
        }
    }

    // ---- hidden = silu(accN + b1) -> bf16, overwrite mi (wave-private rows) ----
    #pragma unroll
    for (int mt = 0; mt < 2; ++mt) {
        const int rowb = (w * 32 + mt * 16 + quad * 4) * MIS;
        #pragma unroll
        for (int nt = 0; nt < 8; ++nt) {
            int col = nt * 16 + ln;
            float b1v = node_b1[col];
            #pragma unroll
            for (int r = 0; r < 4; ++r)
                mi[rowb + r * MIS + col] = f2bf(silu_f(accN[mt][nt][r] + b1v));
        }
    }

    // ---- GEMM2-node: [128,128] @ [128,64], B from global ----
    f32x4 acc2[2][4];
    #pragma unroll
    for (int a = 0; a < 2; ++a)
        #pragma unroll
        for (int b = 0; b < 4; ++b) acc2[a][b] = zero;
    const unsigned short* nw2T = ws + 40960;
    #pragma unroll
    for (int kc = 0; kc < 4; ++kc) {
        short8 a0 = *(const short8*)&mi[arow0 + kc * 32 + koff];
        short8 a1 = *(const short8*)&mi[arow1 + kc * 32 + koff];
        #pragma unroll
        for (int nt = 0; nt < 4; ++nt) {
            short8 b = *(const short8*)(nw2T + (nt * 16 + ln) * 128 + kc * 32 + koff);
            acc2[0][nt] = __builtin_amdgcn_mfma_f32_16x16x32_bf16(a0, b, acc2[0][nt], 0, 0, 0);
            acc2[1][nt] = __builtin_amdgcn_mfma_f32_16x16x32_bf16(a1, b, acc2[1][nt], 0, 0, 0);
        }
    }
    // ---- node scatter: out_h[dst] += m + b2 ----
    #pragma unroll
    for (int mt = 0; mt < 2; ++mt) {
        #pragma unroll
        for (int r = 0; r < 4; ++r) {
            int lrow = w * 32 + mt * 16 + quad * 4 + r;
            int dn = eidx[NE + e0 + lrow];
            float* outrow = out_h + (size_t)dn * 64;
            #pragma unroll
            for (int nt = 0; nt < 4; ++nt) {
                int col = nt * 16 + ln;
                atomicAdd(outrow + col, acc2[mt][nt][r] + node_b2[col]);
            }
        }
    }

    // ---- coord scatter ----
    #pragma unroll
    for (int off = 1; off < 16; off <<= 1) {
        #pragma unroll
        for (int mt = 0; mt < 2; ++mt)
            #pragma unroll
            for (int r = 0; r < 4; ++r)
                cw[mt][r] += __shfl_xor(cw[mt][r], off, 64);
    }
    if (ln < 8) {
        const int smt = ln >> 2, sr = ln & 3;
        float cwsel = 0.f;
        #pragma unroll
        for (int mt = 0; mt < 2; ++mt)
            #pragma unroll
            for (int r = 0; r < 4; ++r)
                cwsel = (mt == smt && r == sr) ? cw[mt][r] : cwsel;
        int lrow = w * 32 + smt * 16 + quad * 4 + sr;
        int s = eidx[e0 + lrow], dn = eidx[NE + e0 + lrow];
        float dx = x[s * 3]     - x[dn * 3];
        float dy = x[s * 3 + 1] - x[dn * 3 + 1];
        float dz = x[s * 3 + 2] - x[dn * 3 + 2];
        float len = fmaxf(sqrtf(dx * dx + dy * dy + dz * dz), 1e-8f);
        float k = cwsel / len;
        atomicAdd(out_x + dn * 3,     k * dx);
        atomicAdd(out_x + dn * 3 + 1, k * dy);
        atomicAdd(out_x + dn * 3 + 2, k * dz);
    }
}

extern "C" void kernel_launch(void* const* d_in, const int* in_sizes, int n_in,
                              void* d_out, int out_size, void* d_ws, size_t ws_size,
                              hipStream_t stream) {
    const float* h    = (const float*)d_in[0];
    const float* x    = (const float*)d_in[1];
    const int*   eidx = (const int*)d_in[2];
    const float* edist= (const float*)d_in[3];
    const float* nw1  = (const float*)d_in[4];
    const float* nb1  = (const float*)d_in[5];
    const float* nw2  = (const float*)d_in[6];
    const float* nb2  = (const float*)d_in[7];
    const float* cw1  = (const float*)d_in[8];
    const float* cb1  = (const float*)d_in[9];
    const float* cw2  = (const float*)d_in[10];
    const float* ew1  = (const float*)d_in[11];
    const float* eb1  = (const float*)d_in[12];
    const float* ew2  = (const float*)d_in[13];
    const float* eb2  = (const float*)d_in[14];
    float* out = (float*)d_out;
    unsigned short* ws = (unsigned short*)d_ws;

    prep_w<<<192, 256, 0, stream>>>(nw1, cw1, nw2, ws);
    prep_h<<<3125, 256, 0, stream>>>((const float4*)h, ws + 65536);
    init_out<<<3272, 256, 0, stream>>>((const float4*)h, (const float4*)x, (float4*)out);
    egnn_edge_kernel<<<NE / BE, 256, 0, stream>>>(x, eidx, edist,
                                                  nb1, nb2, cb1, cw2,
                                                  ew1, eb1, ew2, eb2,
                                                  ws, out, out + 3200000);
}

// Round 3
// 1044.911 us; speedup vs baseline: 1.0698x; 1.0698x over previous
//
#include <hip/hip_runtime.h>
#include <stdint.h>

#define NN 50000
#define NE 1600000
#define BE 128
#define MIS 168   // m_input row stride (ushorts)

// int-unit offsets into ws
#define I_CNT  1632768
#define I_CUR  1732800
#define I_PERM 1782848
#define I_BSUM 3382848

typedef __attribute__((ext_vector_type(8))) short short8;
typedef __attribute__((ext_vector_type(4))) float f32x4;

__device__ __forceinline__ unsigned short f2bf(float f) {
    unsigned int u = __float_as_uint(f);
    u += 0x7fff + ((u >> 16) & 1);
    return (unsigned short)(u >> 16);
}

__device__ __forceinline__ float silu_f(float v) {
    return v / (1.0f + __expf(-v));
}

// ws ushort layout: [0,20480) nw1^T [128][160]; [20480,40960) cw1^T; [40960,49152) nw2^T [64][128]
// ws+65536: h bf16 [50000][64]
__global__ void prep_w(const float* __restrict__ nw1,
                       const float* __restrict__ cw1,
                       const float* __restrict__ nw2,
                       unsigned short* __restrict__ ws) {
    int i = blockIdx.x * 256 + threadIdx.x;
    if (i < 20480) {
        int n = i / 160, k = i % 160;
        ws[i] = f2bf(nw1[k * 128 + n]);
    } else if (i < 40960) {
        int j = i - 20480; int n = j / 160, k = j % 160;
        ws[i] = f2bf(cw1[k * 128 + n]);
    } else if (i < 49152) {
        int j = i - 40960; int o = j / 128, k = j % 128;
        ws[i] = f2bf(nw2[k * 64 + o]);
    }
}

__global__ void prep_h(const float4* __restrict__ h4,
                       unsigned short* __restrict__ hbf) {
    int i = blockIdx.x * 256 + threadIdx.x;
    if (i < 800000) {
        float4 v = h4[i];
        unsigned short b[4] = {f2bf(v.x), f2bf(v.y), f2bf(v.z), f2bf(v.w)};
        *(uint2*)&hbf[i * 4] = *(uint2*)b;
    }
}

__global__ void init_out(const float4* __restrict__ h4,
                         const float4* __restrict__ x4,
                         float4* __restrict__ out4) {
    int i = blockIdx.x * 256 + threadIdx.x;
    if (i < 800000)       out4[i] = h4[i];
    else if (i < 837500)  out4[i] = x4[i - 800000];
}

// ---------- counting sort of edges by dst ----------
__global__ void zero_cnt(int* __restrict__ cnt) {
    int i = blockIdx.x * 256 + threadIdx.x;
    if (i < NN) cnt[i] = 0;
}

__global__ void hist_k(const int* __restrict__ eidx, int* __restrict__ cnt) {
    int e = blockIdx.x * 256 + threadIdx.x;
    if (e < NE) atomicAdd(&cnt[eidx[NE + e]], 1);
}

__global__ void scan_sum(const int* __restrict__ cnt, int* __restrict__ bsum) {
    int i = blockIdx.x * 256 + threadIdx.x;
    int v = (i < NN) ? cnt[i] : 0;
    #pragma unroll
    for (int off = 32; off; off >>= 1) v += __shfl_down(v, off, 64);
    __shared__ int w4[4];
    if ((threadIdx.x & 63) == 0) w4[threadIdx.x >> 6] = v;
    __syncthreads();
    if (threadIdx.x == 0) bsum[blockIdx.x] = w4[0] + w4[1] + w4[2] + w4[3];
}

__global__ void scan_top(int* __restrict__ bsum) {
    __shared__ int s[256];
    int tid = threadIdx.x;
    int v = (tid < 196) ? bsum[tid] : 0;
    s[tid] = v;
    __syncthreads();
    for (int off = 1; off < 256; off <<= 1) {
        int t = (tid >= off) ? s[tid - off] : 0;
        __syncthreads();
        s[tid] += t;
        __syncthreads();
    }
    if (tid < 196) bsum[tid] = s[tid] - v;   // exclusive
}

__global__ void scan_final(const int* __restrict__ cnt, const int* __restrict__ bsum,
                           int* __restrict__ cur) {
    __shared__ int s[256];
    int tid = threadIdx.x, i = blockIdx.x * 256 + tid;
    int v = (i < NN) ? cnt[i] : 0;
    s[tid] = v;
    __syncthreads();
    for (int off = 1; off < 256; off <<= 1) {
        int t = (tid >= off) ? s[tid - off] : 0;
        __syncthreads();
        s[tid] += t;
        __syncthreads();
    }
    if (i < NN) cur[i] = s[tid] - v + bsum[blockIdx.x];
}

__global__ void scatter_k(const int* __restrict__ eidx, int* __restrict__ cur,
                          int* __restrict__ perm) {
    int e = blockIdx.x * 256 + threadIdx.x;
    if (e < NE) {
        int d = eidx[NE + e];
        int pos = atomicAdd(&cur[d], 1);
        perm[pos] = e;
    }
}

// ---------- main fused edge kernel (dst-sorted) ----------
__global__ __launch_bounds__(256, 2)
void egnn_edge_kernel(const float* __restrict__ x,
                      const int* __restrict__ eidx,
                      const float* __restrict__ edist,
                      const int* __restrict__ perm,
                      const float* __restrict__ node_b1,
                      const float* __restrict__ node_b2,
                      const float* __restrict__ coord_b1,
                      const float* __restrict__ coord_w2,
                      const float* __restrict__ ew1,
                      const float* __restrict__ eb1,
                      const float* __restrict__ ew2,
                      const float* __restrict__ eb2,
                      const unsigned short* __restrict__ wsg,
                      float* __restrict__ out_h,
                      float* __restrict__ out_x) {
    __shared__ unsigned short mi[BE * MIS];     // 43008 B; later reused as float mF[128*65]
    __shared__ unsigned short wbuf[64 * MIS];   // 21504 B
    __shared__ int elds[BE], srcv[BE], dstv[BE];
    __shared__ float cu[BE * 4];                // coord updates per row
    __shared__ int sstart[BE], send[BE], sdst[BE];
    __shared__ int nseg;

    const int tid  = threadIdx.x;
    const int w    = tid >> 6;
    const int lane = tid & 63;
    const int ln   = lane & 15;
    const int quad = lane >> 4;
    const int p0   = blockIdx.x * BE;
    const unsigned short* hbf = wsg + 65536;

    // ---- phase 0: sorted edge ids + src/dst into LDS ----
    if (tid < BE) {
        int e = perm[p0 + tid];
        elds[tid] = e;
        srcv[tid] = eidx[e];
        dstv[tid] = eidx[NE + e];
    }
    if (tid == 0) nseg = 0;
    __syncthreads();

    // ---- phase 1a: gather bf16 h[src]|h[dst] into mi ----
    #pragma unroll
    for (int it = 0; it < 8; ++it) {
        int idx = it * 256 + tid;          // 256 rows x 8 chunks
        int row = idx >> 3, chunk = idx & 7;
        int e = row & 127;
        int node = (row < 128) ? srcv[e] : dstv[e];
        int cbase = (row < 128) ? 0 : 64;
        *(uint4*)&mi[e * MIS + cbase + chunk * 8] =
            *(const uint4*)&hbf[node * 64 + chunk * 8];
    }
    // ---- phase 1a': edge MLP -> cols 128..159 ----
    {
        int er = tid >> 1, half = tid & 1;
        float d = edist[elds[er]];
        float s[16];
        #pragma unroll
        for (int jj = 0; jj < 16; ++jj) s[jj] = eb2[half * 16 + jj];
        #pragma unroll
        for (int k = 0; k < 32; ++k) {
            float tk = silu_f(d * ew1[k] + eb1[k]);
            const float* r2 = ew2 + k * 32 + half * 16;
            #pragma unroll
            for (int jj = 0; jj < 16; ++jj) s[jj] += tk * r2[jj];
        }
        #pragma unroll
        for (int jj = 0; jj < 16; ++jj)
            mi[er * MIS + 128 + half * 16 + jj] = f2bf(s[jj]);
    }
    // ---- phase 1b: segment detection over sorted dstv ----
    if (tid < BE) {
        bool isStart = (tid == 0) || (dstv[tid] != dstv[tid - 1]);
        if (isStart) {
            int end = tid + 1;
            while (end < BE && dstv[end] == dstv[tid]) ++end;
            int idx = atomicAdd(&nseg, 1);
            sstart[idx] = tid; send[idx] = end; sdst[idx] = dstv[tid];
        }
    }

    // ---- GEMM1: node + coord (wbuf-staged B, 4 passes) ----
    f32x4 accN[2][8];
    const f32x4 zero = {0.f, 0.f, 0.f, 0.f};
    #pragma unroll
    for (int a = 0; a < 2; ++a)
        #pragma unroll
        for (int b = 0; b < 8; ++b) accN[a][b] = zero;
    float cw[2][4];
    #pragma unroll
    for (int mt = 0; mt < 2; ++mt)
        #pragma unroll
        for (int r = 0; r < 4; ++r) cw[mt][r] = 0.f;

    const int arow0 = (w * 32 + ln) * MIS;
    const int arow1 = (w * 32 + 16 + ln) * MIS;
    const int koff  = quad * 8;

    #pragma unroll
    for (int pass = 0; pass < 4; ++pass) {
        const int mat = pass >> 1, half = pass & 1;
        const unsigned short* wsrc = wsg + mat * 20480 + half * 64 * 160;
        __syncthreads();   // protect prior wbuf reads (pass 0: staging barrier)
        #pragma unroll
        for (int c = 0; c < 5; ++c) {
            int idx = c * 256 + tid;               // 64 rows x 20 chunks
            int row = idx / 20, col8 = idx % 20;
            *(uint4*)&wbuf[row * MIS + col8 * 8] =
                *(const uint4*)(wsrc + row * 160 + col8 * 8);
        }
        __syncthreads();
        f32x4 accC[2][4];
        #pragma unroll
        for (int a = 0; a < 2; ++a)
            #pragma unroll
            for (int b = 0; b < 4; ++b) accC[a][b] = zero;
        #pragma unroll
        for (int kc = 0; kc < 5; ++kc) {
            short8 a0 = *(const short8*)&mi[arow0 + kc * 32 + koff];
            short8 a1 = *(const short8*)&mi[arow1 + kc * 32 + koff];
            #pragma unroll
            for (int nt = 0; nt < 4; ++nt) {
                short8 b = *(const short8*)&wbuf[(nt * 16 + ln) * MIS + kc * 32 + koff];
                if (mat == 0) {
                    const int nn = half * 4 + nt;
                    accN[0][nn] = __builtin_amdgcn_mfma_f32_16x16x32_bf16(a0, b, accN[0][nn], 0, 0, 0);
                    accN[1][nn] = __builtin_amdgcn_mfma_f32_16x16x32_bf16(a1, b, accN[1][nn], 0, 0, 0);
                } else {
                    accC[0][nt] = __builtin_amdgcn_mfma_f32_16x16x32_bf16(a0, b, accC[0][nt], 0, 0, 0);
                    accC[1][nt] = __builtin_amdgcn_mfma_f32_16x16x32_bf16(a1, b, accC[1][nt], 0, 0, 0);
                }
            }
        }
        if (mat == 1) {
            #pragma unroll
            for (int nt = 0; nt < 4; ++nt) {
                int col = half * 64 + nt * 16 + ln;
                float b1v = coord_b1[col];
                float w2v = coord_w2[col];
                #pragma unroll
                for (int mt = 0; mt < 2; ++mt)
                    #pragma unroll
                    for (int r = 0; r < 4; ++r)
                        cw[mt][r] += silu_f(accC[mt][nt][r] + b1v) * w2v;
            }
        }
    }

    // ---- hidden = silu(accN+b1) -> bf16, wave-private rows of mi ----
    #pragma unroll
    for (int mt = 0; mt < 2; ++mt) {
        const int rowb = (w * 32 + mt * 16 + quad * 4) * MIS;
        #pragma unroll
        for (int nt = 0; nt < 8; ++nt) {
            int col = nt * 16 + ln;
            float b1v = node_b1[col];
            #pragma unroll
            for (int r = 0; r < 4; ++r)
                mi[rowb + r * MIS + col] = f2bf(silu_f(accN[mt][nt][r] + b1v));
        }
    }

    // ---- GEMM2-node: [128,128]@[128,64], B from global ----
    f32x4 acc2[2][4];
    #pragma unroll
    for (int a = 0; a < 2; ++a)
        #pragma unroll
        for (int b = 0; b < 4; ++b) acc2[a][b] = zero;
    const unsigned short* nw2T = wsg + 40960;
    #pragma unroll
    for (int kc = 0; kc < 4; ++kc) {
        short8 a0 = *(const short8*)&mi[arow0 + kc * 32 + koff];
        short8 a1 = *(const short8*)&mi[arow1 + kc * 32 + koff];
        #pragma unroll
        for (int nt = 0; nt < 4; ++nt) {
            short8 b = *(const short8*)(nw2T + (nt * 16 + ln) * 128 + kc * 32 + koff);
            acc2[0][nt] = __builtin_amdgcn_mfma_f32_16x16x32_bf16(a0, b, acc2[0][nt], 0, 0, 0);
            acc2[1][nt] = __builtin_amdgcn_mfma_f32_16x16x32_bf16(a1, b, acc2[1][nt], 0, 0, 0);
        }
    }

    // ---- write m tile (fp32, stride 65) + coord updates into LDS ----
    __syncthreads();   // all GEMM2 reads of mi done before float overwrite
    float* mF = (float*)mi;
    #pragma unroll
    for (int mt = 0; mt < 2; ++mt) {
        #pragma unroll
        for (int nt = 0; nt < 4; ++nt) {
            int col = nt * 16 + ln;
            float b2v = node_b2[col];
            #pragma unroll
            for (int r = 0; r < 4; ++r) {
                int row = w * 32 + mt * 16 + quad * 4 + r;
                mF[row * 65 + col] = acc2[mt][nt][r] + b2v;
            }
        }
    }
    // coord scalar: reduce cw across the 16 col-lanes
    #pragma unroll
    for (int off = 1; off < 16; off <<= 1) {
        #pragma unroll
        for (int mt = 0; mt < 2; ++mt)
            #pragma unroll
            for (int r = 0; r < 4; ++r)
                cw[mt][r] += __shfl_xor(cw[mt][r], off, 64);
    }
    if (ln < 8) {
        const int smt = ln >> 2, sr = ln & 3;
        float cwsel = 0.f;
        #pragma unroll
        for (int mt = 0; mt < 2; ++mt)
            #pragma unroll
            for (int r = 0; r < 4; ++r)
                cwsel = (mt == smt && r == sr) ? cw[mt][r] : cwsel;
        int lrow = w * 32 + smt * 16 + quad * 4 + sr;
        int s = srcv[lrow], dn = dstv[lrow];
        float dx = x[s * 3]     - x[dn * 3];
        float dy = x[s * 3 + 1] - x[dn * 3 + 1];
        float dz = x[s * 3 + 2] - x[dn * 3 + 2];
        float len = fmaxf(sqrtf(dx * dx + dy * dy + dz * dz), 1e-8f);
        float k = cwsel / len;
        cu[lrow * 4 + 0] = k * dx;
        cu[lrow * 4 + 1] = k * dy;
        cu[lrow * 4 + 2] = k * dz;
    }
    __syncthreads();

    // ---- per-segment reduction + one atomic per (segment, col) ----
    int ns = nseg;
    for (int s = w; s < ns; s += 4) {
        int a = sstart[s], b = send[s], dn = sdst[s];
        float acc = 0.f;
        for (int r = a; r < b; ++r) acc += mF[r * 65 + lane];
        atomicAdd(out_h + (size_t)dn * 64 + lane, acc);
        if (lane < 3) {
            float c3 = 0.f;
            for (int r = a; r < b; ++r) c3 += cu[r * 4 + lane];
            atomicAdd(out_x + dn * 3 + lane, c3);
        }
    }
}

extern "C" void kernel_launch(void* const* d_in, const int* in_sizes, int n_in,
                              void* d_out, int out_size, void* d_ws, size_t ws_size,
                              hipStream_t stream) {
    const float* h    = (const float*)d_in[0];
    const float* x    = (const float*)d_in[1];
    const int*   eidx = (const int*)d_in[2];
    const float* edist= (const float*)d_in[3];
    const float* nw1  = (const float*)d_in[4];
    const float* nb1  = (const float*)d_in[5];
    const float* nw2  = (const float*)d_in[6];
    const float* nb2  = (const float*)d_in[7];
    const float* cw1  = (const float*)d_in[8];
    const float* cb1  = (const float*)d_in[9];
    const float* cw2  = (const float*)d_in[10];
    const float* ew1  = (const float*)d_in[11];
    const float* eb1  = (const float*)d_in[12];
    const float* ew2  = (const float*)d_in[13];
    const float* eb2  = (const float*)d_in[14];
    float* out = (float*)d_out;
    unsigned short* ws = (unsigned short*)d_ws;
    int* wsi = (int*)d_ws;

    prep_w<<<192, 256, 0, stream>>>(nw1, cw1, nw2, ws);
    prep_h<<<3125, 256, 0, stream>>>((const float4*)h, ws + 65536);
    zero_cnt<<<196, 256, 0, stream>>>(wsi + I_CNT);
    hist_k<<<6250, 256, 0, stream>>>(eidx, wsi + I_CNT);
    scan_sum<<<196, 256, 0, stream>>>(wsi + I_CNT, wsi + I_BSUM);
    scan_top<<<1, 256, 0, stream>>>(wsi + I_BSUM);
    scan_final<<<196, 256, 0, stream>>>(wsi + I_CNT, wsi + I_BSUM, wsi + I_CUR);
    scatter_k<<<6250, 256, 0, stream>>>(eidx, wsi + I_CUR, wsi + I_PERM);
    init_out<<<3272, 256, 0, stream>>>((const float4*)h, (const float4*)x, (float4*)out);
    egnn_edge_kernel<<<NE / BE, 256, 0, stream>>>(x, eidx, edist, wsi + I_PERM,
                                                  nb1, nb2, cb1, cw2,
                                                  ew1, eb1, ew2, eb2,
                                                  ws, out, out + 3200000);
}

// Round 4
// 838.923 us; speedup vs baseline: 1.3325x; 1.2455x over previous
//
#include <hip/hip_runtime.h>
#include <stdint.h>

#define NN 50000
#define NE 1600000
#define BE 128
#define MIS 168   // m_input row stride (ushorts)

// ws offsets
// ushort units: [0,20480) W1'^T node [128n][160k] (k>=128 = fused edge V)
//               [20480,40960) W1'^T coord ; [40960,49152) nw2^T [64][128]
//               49152: float[256] fused biases (b1n'[128], b1c'[128])
//               65536: h bf16 [50000][64]
#define U_HBF  65536
// int units:
#define I_CNT  1632768
#define I_CUR  1682768
#define I_BSUM 1732768
// ushort units:
#define S_SRC  3466048
#define S_DST  5066048
// float units:
#define F_DIST 3333024

typedef __attribute__((ext_vector_type(8))) short short8;
typedef __attribute__((ext_vector_type(4))) float f32x4;

__device__ __forceinline__ unsigned short f2bf(float f) {
    unsigned int u = __float_as_uint(f);
    u += 0x7fff + ((u >> 16) & 1);
    return (unsigned short)(u >> 16);
}

__device__ __forceinline__ float silu_f(float v) {
    return v / (1.0f + __expf(-v));
}

// ---------- merged prep: h->bf16 | out init | zero cnt | fused W1' | W2T | fused biases ----------
__global__ void prep_all(const float4* __restrict__ h4,
                         const float4* __restrict__ x4,
                         const float* __restrict__ nw1, const float* __restrict__ nb1,
                         const float* __restrict__ nw2,
                         const float* __restrict__ cw1, const float* __restrict__ cb1,
                         const float* __restrict__ ew2, const float* __restrict__ eb2,
                         unsigned short* __restrict__ ws,
                         int* __restrict__ cnt,
                         float4* __restrict__ out4) {
    int b = blockIdx.x, t = threadIdx.x;
    if (b < 3125) {                       // h -> bf16
        int i = b * 256 + t;
        if (i < 800000) {
            float4 v = h4[i];
            unsigned short p[4] = {f2bf(v.x), f2bf(v.y), f2bf(v.z), f2bf(v.w)};
            *(uint2*)&ws[U_HBF + i * 4] = *(uint2*)p;
        }
    } else if (b < 6397) {                // out = [h | x]
        int i = (b - 3125) * 256 + t;
        if (i < 800000)       out4[i] = h4[i];
        else if (i < 837500)  out4[i] = x4[i - 800000];
    } else if (b < 6593) {                // zero histogram
        int i = (b - 6397) * 256 + t;
        if (i < NN) cnt[i] = 0;
    } else if (b < 6753) {                // W1' (transpose + fused edge-V)
        int idx = (b - 6593) * 256 + t;   // [0,40960)
        int mat = idx / 20480, r = idx % 20480;
        int n = r / 160, k = r % 160;
        const float* W1 = mat ? cw1 : nw1;
        float v;
        if (k < 128) v = W1[k * 128 + n];
        else {
            int j = k - 128;
            v = 0.f;
            for (int c = 0; c < 32; ++c)
                v += ew2[j * 32 + c] * W1[(128 + c) * 128 + n];
        }
        ws[mat * 20480 + n * 160 + k] = f2bf(v);
    } else if (b < 6785) {                // W2^T
        int idx = (b - 6753) * 256 + t;   // [0,8192)
        int o = idx / 128, k = idx % 128;
        ws[40960 + o * 128 + k] = f2bf(nw2[k * 64 + o]);
    } else {                              // fused biases (fp32)
        float* fb = (float*)(ws + 49152);
        if (t < 128) {
            float v = nb1[t];
            for (int c = 0; c < 32; ++c) v += eb2[c] * nw1[(128 + c) * 128 + t];
            fb[t] = v;
        } else if (t < 256) {
            int tt = t - 128;
            float v = cb1[tt];
            for (int c = 0; c < 32; ++c) v += eb2[c] * cw1[(128 + c) * 128 + tt];
            fb[128 + tt] = v;
        }
    }
}

// ---------- counting sort by dst ----------
__global__ void hist_k(const int* __restrict__ eidx, int* __restrict__ cnt) {
    int e = blockIdx.x * 256 + threadIdx.x;
    if (e < NE) atomicAdd(&cnt[eidx[NE + e]], 1);
}

__global__ void scan_sum(const int* __restrict__ cnt, int* __restrict__ bsum) {
    int i = blockIdx.x * 256 + threadIdx.x;
    int v = (i < NN) ? cnt[i] : 0;
    #pragma unroll
    for (int off = 32; off; off >>= 1) v += __shfl_down(v, off, 64);
    __shared__ int w4[4];
    if ((threadIdx.x & 63) == 0) w4[threadIdx.x >> 6] = v;
    __syncthreads();
    if (threadIdx.x == 0) bsum[blockIdx.x] = w4[0] + w4[1] + w4[2] + w4[3];
}

__global__ void scan_top(int* __restrict__ bsum) {
    __shared__ int s[256];
    int tid = threadIdx.x;
    int v = (tid < 196) ? bsum[tid] : 0;
    s[tid] = v;
    __syncthreads();
    for (int off = 1; off < 256; off <<= 1) {
        int t = (tid >= off) ? s[tid - off] : 0;
        __syncthreads();
        s[tid] += t;
        __syncthreads();
    }
    if (tid < 196) bsum[tid] = s[tid] - v;
}

__global__ void scan_final(const int* __restrict__ cnt, const int* __restrict__ bsum,
                           int* __restrict__ cur) {
    __shared__ int s[256];
    int tid = threadIdx.x, i = blockIdx.x * 256 + tid;
    int v = (i < NN) ? cnt[i] : 0;
    s[tid] = v;
    __syncthreads();
    for (int off = 1; off < 256; off <<= 1) {
        int t = (tid >= off) ? s[tid - off] : 0;
        __syncthreads();
        s[tid] += t;
        __syncthreads();
    }
    if (i < NN) cur[i] = s[tid] - v + bsum[blockIdx.x];
}

// materialize sorted src/dst/dist (scattered fire-and-forget writes)
__global__ void scatter_k(const int* __restrict__ eidx, const float* __restrict__ edist,
                          int* __restrict__ cur,
                          unsigned short* __restrict__ ssrc,
                          unsigned short* __restrict__ sdst,
                          float* __restrict__ fdist) {
    int e = blockIdx.x * 256 + threadIdx.x;
    if (e < NE) {
        int s = eidx[e], d = eidx[NE + e];
        int pos = atomicAdd(&cur[d], 1);
        ssrc[pos] = (unsigned short)s;
        sdst[pos] = (unsigned short)d;
        fdist[pos] = edist[e];
    }
}

// ---------- main fused edge kernel (dst-sorted, coalesced inputs) ----------
__global__ __launch_bounds__(256, 3)
void egnn_edge_kernel(const float* __restrict__ x,
                      const unsigned short* __restrict__ ssrc,
                      const unsigned short* __restrict__ sdst,
                      const float* __restrict__ fdist,
                      const float* __restrict__ node_b2,
                      const float* __restrict__ coord_w2,
                      const float* __restrict__ ew1,
                      const float* __restrict__ eb1,
                      const unsigned short* __restrict__ wsg,
                      float* __restrict__ out_h,
                      float* __restrict__ out_x) {
    __shared__ unsigned short mi[BE * MIS];   // 43008 B; later float mF[128*65]
    __shared__ int srcv[BE], dstv[BE];
    __shared__ float cu[BE * 4];
    __shared__ int sstart[BE], send[BE], sdseg[BE];
    __shared__ int nseg;

    const int tid  = threadIdx.x;
    const int w    = tid >> 6;
    const int lane = tid & 63;
    const int ln   = lane & 15;
    const int quad = lane >> 4;
    const int p0   = blockIdx.x * BE;
    const unsigned short* hbf = wsg + U_HBF;
    const float* fb = (const float*)(wsg + 49152);

    // ---- phase 0: coalesced sorted src/dst ----
    if (tid < BE) {
        srcv[tid] = ssrc[p0 + tid];
        dstv[tid] = sdst[p0 + tid];
    }
    if (tid == 0) nseg = 0;
    __syncthreads();

    // ---- gather bf16 h[src]|h[dst] ----
    #pragma unroll
    for (int it = 0; it < 8; ++it) {
        int idx = it * 256 + tid;          // 256 rows x 8 chunks
        int row = idx >> 3, chunk = idx & 7;
        int e = row & 127;
        int node = (row < 128) ? srcv[e] : dstv[e];
        int cbase = (row < 128) ? 0 : 64;
        *(uint4*)&mi[e * MIS + cbase + chunk * 8] =
            *(const uint4*)&hbf[node * 64 + chunk * 8];
    }
    // ---- cols 128..159: silu(d*ew1+eb1) (edge MLP folded into W1') ----
    {
        int er = tid >> 1, half = tid & 1;
        float d = fdist[p0 + er];
        #pragma unroll
        for (int jj = 0; jj < 16; ++jj) {
            int j = half * 16 + jj;
            float t = fmaf(d, ew1[j], eb1[j]);
            mi[er * MIS + 128 + half * 16 + jj] = f2bf(silu_f(t));
        }
    }
    // ---- segment detection on sorted dstv ----
    if (tid < BE) {
        bool isStart = (tid == 0) || (dstv[tid] != dstv[tid - 1]);
        if (isStart) {
            int end = tid + 1;
            while (end < BE && dstv[end] == dstv[tid]) ++end;
            int idx = atomicAdd(&nseg, 1);
            sstart[idx] = tid; send[idx] = end; sdseg[idx] = dstv[tid];
        }
    }
    __syncthreads();

    // ---- GEMM1: node + coord, B direct from global (L1-resident 80KB) ----
    f32x4 accN[2][8];
    const f32x4 zero = {0.f, 0.f, 0.f, 0.f};
    #pragma unroll
    for (int a = 0; a < 2; ++a)
        #pragma unroll
        for (int b = 0; b < 8; ++b) accN[a][b] = zero;
    float cw[2][4];
    #pragma unroll
    for (int mt = 0; mt < 2; ++mt)
        #pragma unroll
        for (int r = 0; r < 4; ++r) cw[mt][r] = 0.f;

    const int arow0 = (w * 32 + ln) * MIS;
    const int arow1 = (w * 32 + 16 + ln) * MIS;
    const int koff  = quad * 8;
    const unsigned short* WN = wsg;
    const unsigned short* WC = wsg + 20480;

    #pragma unroll
    for (int half = 0; half < 2; ++half) {
        f32x4 accC[2][4];
        #pragma unroll
        for (int a = 0; a < 2; ++a)
            #pragma unroll
            for (int b = 0; b < 4; ++b) accC[a][b] = zero;
        #pragma unroll
        for (int kc = 0; kc < 5; ++kc) {
            short8 a0 = *(const short8*)&mi[arow0 + kc * 32 + koff];
            short8 a1 = *(const short8*)&mi[arow1 + kc * 32 + koff];
            #pragma unroll
            for (int nt = 0; nt < 4; ++nt) {
                const int rofs = (half * 64 + nt * 16 + ln) * 160 + kc * 32 + koff;
                short8 bN = *(const short8*)(WN + rofs);
                short8 bC = *(const short8*)(WC + rofs);
                const int nn = half * 4 + nt;
                accN[0][nn] = __builtin_amdgcn_mfma_f32_16x16x32_bf16(a0, bN, accN[0][nn], 0, 0, 0);
                accN[1][nn] = __builtin_amdgcn_mfma_f32_16x16x32_bf16(a1, bN, accN[1][nn], 0, 0, 0);
                accC[0][nt] = __builtin_amdgcn_mfma_f32_16x16x32_bf16(a0, bC, accC[0][nt], 0, 0, 0);
                accC[1][nt] = __builtin_amdgcn_mfma_f32_16x16x32_bf16(a1, bC, accC[1][nt], 0, 0, 0);
            }
        }
        // fold coord half -> scalar cw
        #pragma unroll
        for (int nt = 0; nt < 4; ++nt) {
            int col = half * 64 + nt * 16 + ln;
            float b1v = fb[128 + col];
            float w2v = coord_w2[col];
            #pragma unroll
            for (int mt = 0; mt < 2; ++mt)
                #pragma unroll
                for (int r = 0; r < 4; ++r)
                    cw[mt][r] += silu_f(accC[mt][nt][r] + b1v) * w2v;
        }
    }

    // ---- hidden = silu(accN + b1') -> bf16, wave-private rows of mi ----
    #pragma unroll
    for (int mt = 0; mt < 2; ++mt) {
        const int rowb = (w * 32 + mt * 16 + quad * 4) * MIS;
        #pragma unroll
        for (int nt = 0; nt < 8; ++nt) {
            int col = nt * 16 + ln;
            float b1v = fb[col];
            #pragma unroll
            for (int r = 0; r < 4; ++r)
                mi[rowb + r * MIS + col] = f2bf(silu_f(accN[mt][nt][r] + b1v));
        }
    }

    // ---- GEMM2-node, B from global ----
    f32x4 acc2[2][4];
    #pragma unroll
    for (int a = 0; a < 2; ++a)
        #pragma unroll
        for (int b = 0; b < 4; ++b) acc2[a][b] = zero;
    const unsigned short* nw2T = wsg + 40960;
    #pragma unroll
    for (int kc = 0; kc < 4; ++kc) {
        short8 a0 = *(const short8*)&mi[arow0 + kc * 32 + koff];
        short8 a1 = *(const short8*)&mi[arow1 + kc * 32 + koff];
        #pragma unroll
        for (int nt = 0; nt < 4; ++nt) {
            short8 b = *(const short8*)(nw2T + (nt * 16 + ln) * 128 + kc * 32 + koff);
            acc2[0][nt] = __builtin_amdgcn_mfma_f32_16x16x32_bf16(a0, b, acc2[0][nt], 0, 0, 0);
            acc2[1][nt] = __builtin_amdgcn_mfma_f32_16x16x32_bf16(a1, b, acc2[1][nt], 0, 0, 0);
        }
    }

    // ---- write m tile (fp32, stride 65) + coord updates to LDS ----
    __syncthreads();   // protect other waves' mi A-reads before float overwrite
    float* mF = (float*)mi;
    #pragma unroll
    for (int mt = 0; mt < 2; ++mt) {
        #pragma unroll
        for (int nt = 0; nt < 4; ++nt) {
            int col = nt * 16 + ln;
            float b2v = node_b2[col];
            #pragma unroll
            for (int r = 0; r < 4; ++r) {
                int row = w * 32 + mt * 16 + quad * 4 + r;
                mF[row * 65 + col] = acc2[mt][nt][r] + b2v;
            }
        }
    }
    #pragma unroll
    for (int off = 1; off < 16; off <<= 1) {
        #pragma unroll
        for (int mt = 0; mt < 2; ++mt)
            #pragma unroll
            for (int r = 0; r < 4; ++r)
                cw[mt][r] += __shfl_xor(cw[mt][r], off, 64);
    }
    if (ln < 8) {
        const int smt = ln >> 2, sr = ln & 3;
        float cwsel = 0.f;
        #pragma unroll
        for (int mt = 0; mt < 2; ++mt)
            #pragma unroll
            for (int r = 0; r < 4; ++r)
                cwsel = (mt == smt && r == sr) ? cw[mt][r] : cwsel;
        int lrow = w * 32 + smt * 16 + quad * 4 + sr;
        int s = srcv[lrow], dn = dstv[lrow];
        float dx = x[s * 3]     - x[dn * 3];
        float dy = x[s * 3 + 1] - x[dn * 3 + 1];
        float dz = x[s * 3 + 2] - x[dn * 3 + 2];
        float len = fmaxf(sqrtf(dx * dx + dy * dy + dz * dz), 1e-8f);
        float k = cwsel / len;
        cu[lrow * 4 + 0] = k * dx;
        cu[lrow * 4 + 1] = k * dy;
        cu[lrow * 4 + 2] = k * dz;
    }
    __syncthreads();

    // ---- per-segment reduce + one atomic per (segment,col) ----
    int ns = nseg;
    for (int s = w; s < ns; s += 4) {
        int a = sstart[s], b = send[s], dn = sdseg[s];
        float acc = 0.f;
        for (int r = a; r < b; ++r) acc += mF[r * 65 + lane];
        atomicAdd(out_h + (size_t)dn * 64 + lane, acc);
        if (lane < 3) {
            float c3 = 0.f;
            for (int r = a; r < b; ++r) c3 += cu[r * 4 + lane];
            atomicAdd(out_x + dn * 3 + lane, c3);
        }
    }
}

extern "C" void kernel_launch(void* const* d_in, const int* in_sizes, int n_in,
                              void* d_out, int out_size, void* d_ws, size_t ws_size,
                              hipStream_t stream) {
    const float* h    = (const float*)d_in[0];
    const float* x    = (const float*)d_in[1];
    const int*   eidx = (const int*)d_in[2];
    const float* edist= (const float*)d_in[3];
    const float* nw1  = (const float*)d_in[4];
    const float* nb1  = (const float*)d_in[5];
    const float* nw2  = (const float*)d_in[6];
    const float* nb2  = (const float*)d_in[7];
    const float* cw1  = (const float*)d_in[8];
    const float* cb1  = (const float*)d_in[9];
    const float* cw2  = (const float*)d_in[10];
    const float* ew1  = (const float*)d_in[11];
    const float* eb1  = (const float*)d_in[12];
    const float* ew2  = (const float*)d_in[13];
    const float* eb2  = (const float*)d_in[14];
    float* out = (float*)d_out;
    unsigned short* ws = (unsigned short*)d_ws;
    int* wsi = (int*)d_ws;
    float* wsf = (float*)d_ws;

    prep_all<<<6786, 256, 0, stream>>>((const float4*)h, (const float4*)x,
                                       nw1, nb1, nw2, cw1, cb1, ew2, eb2,
                                       ws, wsi + I_CNT, (float4*)out);
    hist_k<<<6250, 256, 0, stream>>>(eidx, wsi + I_CNT);
    scan_sum<<<196, 256, 0, stream>>>(wsi + I_CNT, wsi + I_BSUM);
    scan_top<<<1, 256, 0, stream>>>(wsi + I_BSUM);
    scan_final<<<196, 256, 0, stream>>>(wsi + I_CNT, wsi + I_BSUM, wsi + I_CUR);
    scatter_k<<<6250, 256, 0, stream>>>(eidx, edist, wsi + I_CUR,
                                        ws + S_SRC, ws + S_DST, wsf + F_DIST);
    egnn_edge_kernel<<<NE / BE, 256, 0, stream>>>(x, ws + S_SRC, ws + S_DST, wsf + F_DIST,
                                                  nb2, cw2, ew1, eb1,
                                                  ws, out, out + 3200000);
}